// Round 10
// baseline (234.541 us; speedup 1.0000x reference)
//
#include <hip/hip_runtime.h>
#include <hip/hip_bf16.h>
#include <math.h>

#define B_ 256
#define I_ 512
#define H_ 512
#define BH (B_*H_)
#define NCH 8            // h-chunks for hebbdot partials
#define HCH (H_/NCH)     // 64
#define NHEBB (B_*NCH)   // 2048 hebbdot blocks
#define NGATE 512        // gate blocks (x4 waves = 2048 16x16 tiles)

typedef float f4v  __attribute__((ext_vector_type(4)));
typedef short s8v  __attribute__((ext_vector_type(8)));   // 8 bf16
typedef float f32x4 __attribute__((ext_vector_type(4)));

// ws layout (floats):
// [0, 4*BH)        : pre[g][b][k] gate pre-acts WITH biases
// [4*BH, 12*BH)    : part[ch][b][k] hebbdot partials
// [12*BH, 13*BH)   : v[b,k]

// ---------------------------------------------------------------------------
// Fused: blocks [0,2048) hebbdot partials (HBM stream, dispatched first);
// blocks [2048, 2560) gate GEMM via MFMA with in-register fp32->split-bf16
// conversion (no LDS, no barriers -> latency-tolerant under the stream).
// ---------------------------------------------------------------------------
__global__ __launch_bounds__(256) void k_dot_gates(
    const float* __restrict__ hebb, const float* __restrict__ h0,
    const float* __restrict__ inputs,
    const float* __restrict__ Wxf, const float* __restrict__ Whf,
    const float* __restrict__ Wxi, const float* __restrict__ Whi,
    const float* __restrict__ Wxo, const float* __restrict__ Who,
    const float* __restrict__ Wxc, const float* __restrict__ w,
    const float* __restrict__ bxf, const float* __restrict__ bhf,
    const float* __restrict__ bxi, const float* __restrict__ bhi,
    const float* __restrict__ bxo, const float* __restrict__ bho,
    const float* __restrict__ bxc,
    float* __restrict__ pre, float* __restrict__ part) {

    __shared__ float  h0s[HCH];
    __shared__ float4 red[256];
    int bid = blockIdx.x;
    int tid = threadIdx.x;

    if (bid < NHEBB) {
        // ---------------- hebbdot path ----------------
        int b  = bid >> 3;     // consecutive blocks share b -> contiguous hebb
        int ch = bid & 7;
        if (tid < HCH) h0s[tid] = h0[b * H_ + ch * HCH + tid];
        __syncthreads();

        const float4* hbp = (const float4*)(hebb + ((size_t)b * H_ + (size_t)ch * HCH) * H_);
        int tk = tid & 127;    // float4 column
        int th = tid >> 7;     // 0,1 — split h range
        float4 acc = make_float4(0.f, 0.f, 0.f, 0.f);
        #pragma unroll 8
        for (int r = 0; r < 32; ++r) {
            int hh = th * 32 + r;
            float s = h0s[hh];
            float4 vv = hbp[(size_t)hh * 128 + tk];
            acc.x += s * vv.x; acc.y += s * vv.y;
            acc.z += s * vv.z; acc.w += s * vv.w;
        }
        red[tid] = acc;
        __syncthreads();
        if (tid < 128) {
            float4 a = red[tid], c = red[tid + 128];
            float4 o = make_float4(a.x + c.x, a.y + c.y, a.z + c.z, a.w + c.w);
            ((float4*)(part + ((size_t)ch * B_ + b) * H_))[tid] = o;
        }
    } else {
        // ---------------- MFMA gates path, inline split-bf16 convert -------
        int wave = tid >> 6, lane = tid & 63;
        int tile = (bid - NHEBB) * 4 + wave;     // 0..2047
        int m0 = (tile & 15) << 4;               // batch tile
        int n0 = (tile >> 4) << 4;               // virtual gate column tile
        int r  = lane & 15;
        int kg = lane >> 4;                      // k-group (0..3), 8 elems
        int g  = n0 >> 9;
        int ko0 = n0 & 511;
        int ko  = ko0 + r;

        const float* Wx  = (g == 0) ? Wxf : (g == 1) ? Wxi : (g == 2) ? Wxo : Wxc;
        const float* Whp = (g == 0) ? Whf : (g == 1) ? Whi : Who;  // g==3 unused
        const float* arow_i = inputs + (size_t)(m0 + r) * 512;
        const float* arow_h = h0     + (size_t)(m0 + r) * 512;
        const float* brow_x = Wx     + (size_t)ko * 512;
        const float* brow_h = Whp    + (size_t)ko * 512;

        f32x4 acc = {0.f, 0.f, 0.f, 0.f};
        #pragma unroll 2
        for (int kc = 0; kc < 32; ++kc) {
            int kb = kc * 32 + kg * 8;           // global k of this lane's 8
            float a[8], bb[8];
            if (kc < 16) {                       // k < 512: inputs @ Wx
                *(float4*)&a[0]  = *(const float4*)&arow_i[kb];
                *(float4*)&a[4]  = *(const float4*)&arow_i[kb + 4];
                *(float4*)&bb[0] = *(const float4*)&brow_x[kb];
                *(float4*)&bb[4] = *(const float4*)&brow_x[kb + 4];
            } else {                             // k >= 512: h0 @ Wh / w
                int c = kb - 512;
                *(float4*)&a[0] = *(const float4*)&arow_h[c];
                *(float4*)&a[4] = *(const float4*)&arow_h[c + 4];
                if (g < 3) {
                    *(float4*)&bb[0] = *(const float4*)&brow_h[c];
                    *(float4*)&bb[4] = *(const float4*)&brow_h[c + 4];
                } else {
                    #pragma unroll
                    for (int j = 0; j < 8; ++j)   // w transposed on the fly
                        bb[j] = w[(size_t)(c + j) * 512 + ko];
                }
            }
            union { s8v v; ushort u[8]; } Ah, Al, Bh, Bl;
            #pragma unroll
            for (int j = 0; j < 8; ++j) {
                __hip_bfloat16 hx = __float2bfloat16(a[j]);
                float hxf = __bfloat162float(hx);
                __hip_bfloat16 lx = __float2bfloat16(a[j] - hxf);
                Ah.u[j] = *(ushort*)&hx; Al.u[j] = *(ushort*)&lx;
                __hip_bfloat16 hy = __float2bfloat16(bb[j]);
                float hyf = __bfloat162float(hy);
                __hip_bfloat16 ly = __float2bfloat16(bb[j] - hyf);
                Bh.u[j] = *(ushort*)&hy; Bl.u[j] = *(ushort*)&ly;
            }
            acc = __builtin_amdgcn_mfma_f32_16x16x32_bf16(Ah.v, Bh.v, acc, 0, 0, 0);
            acc = __builtin_amdgcn_mfma_f32_16x16x32_bf16(Ah.v, Bl.v, acc, 0, 0, 0);
            acc = __builtin_amdgcn_mfma_f32_16x16x32_bf16(Al.v, Bh.v, acc, 0, 0, 0);
        }

        float bias;
        if (g == 0)      bias = bxf[ko] + bhf[ko];
        else if (g == 1) bias = bxi[ko] + bhi[ko];
        else if (g == 2) bias = bxo[ko] + bho[ko];
        else             bias = bxc[ko];
        #pragma unroll
        for (int j = 0; j < 4; ++j) {            // C/D: row = kg*4 + j
            int m = m0 + kg * 4 + j;
            pre[(size_t)g * BH + (size_t)m * H_ + ko] = acc[j] + bias;
        }
    }
}

// ---------------------------------------------------------------------------
// K2: finalize per sample (pre already has biases)
// ---------------------------------------------------------------------------
__global__ __launch_bounds__(256) void k_finalize(
    const float* __restrict__ pre, const float* __restrict__ part,
    const float* __restrict__ c0, const float* __restrict__ alpha,
    const float* __restrict__ Wmod, const float* __restrict__ bmod,
    const float* __restrict__ Wfan, const float* __restrict__ bfan,
    float* __restrict__ out, float* __restrict__ v) {

    int b = blockIdx.x;
    int t = threadIdx.x;

    float c2r[2];
    float local = 0.f;
    #pragma unroll
    for (int s = 0; s < 2; ++s) {
        int k = t + s * 256;
        float dot = 0.f;
        #pragma unroll
        for (int c = 0; c < NCH; ++c) dot += part[((size_t)c * B_ + b) * H_ + k];
        size_t off = (size_t)b * H_ + k;
        float pf = pre[0 * BH + off];
        float pi = pre[1 * BH + off];
        float po = pre[2 * BH + off];
        float pc = pre[3 * BH + off];
        float c2 = tanhf(pc + alpha[k] * dot);
        float fg = 1.f / (1.f + expf(-pf));
        float ig = 1.f / (1.f + expf(-pi));
        float og = 1.f / (1.f + expf(-po));
        float cell = fg * c0[off] + ig * c2;
        float ha = og * tanhf(cell);
        out[off] = ha;                 // hactiv
        out[BH + off] = cell;          // cell
        c2r[s] = c2;
        local += ha * Wmod[k];
    }
    float x = local;
    #pragma unroll
    for (int o = 32; o > 0; o >>= 1) x += __shfl_down(x, o, 64);
    __shared__ float red[4];
    int wid = t >> 6, lane = t & 63;
    if (lane == 0) red[wid] = x;
    __syncthreads();
    float s4 = red[0] + red[1] + red[2] + red[3];
    float myeta = tanhf(s4 + bmod[0]);
    #pragma unroll
    for (int s = 0; s < 2; ++s) {
        int k = t + s * 256;
        size_t off = (size_t)b * H_ + k;
        v[off] = (myeta * Wfan[k] + bfan[k]) * c2r[s];
    }
}

// ---------------------------------------------------------------------------
// K3: hebb_new = clip(hebb + h0[b,h]*v[b,k], -2, 2)
// Reverse-order stream + NT stores.
// ---------------------------------------------------------------------------
__global__ __launch_bounds__(256) void k_update(
    const float4* __restrict__ hebb, const float* __restrict__ h0,
    const float* __restrict__ v, float* __restrict__ out) {
    const int total = B_ * H_ * (H_ / 4);   // 16,777,216 float4
    int stride = gridDim.x * blockDim.x;    // 524,288
    int base = blockIdx.x * blockDim.x + threadIdx.x;
    for (int f = total - stride + base; f >= 0; f -= stride) {
        int k4 = f & 127;
        int h  = (f >> 7) & 511;
        int b  = f >> 16;
        float u = h0[(b << 9) + h];
        const float4* vv4 = (const float4*)v;
        float4 vv = vv4[(b << 7) + k4];
        float4 hb = hebb[f];
        f4v r;
        r.x = fminf(fmaxf(hb.x + u * vv.x, -2.f), 2.f);
        r.y = fminf(fmaxf(hb.y + u * vv.y, -2.f), 2.f);
        r.z = fminf(fmaxf(hb.z + u * vv.z, -2.f), 2.f);
        r.w = fminf(fmaxf(hb.w + u * vv.w, -2.f), 2.f);
        __builtin_nontemporal_store(r, (f4v*)(out) + f);
    }
}

// ---------------------------------------------------------------------------
extern "C" void kernel_launch(void* const* d_in, const int* in_sizes, int n_in,
                              void* d_out, int out_size, void* d_ws, size_t ws_size,
                              hipStream_t stream) {
    const float* inputs = (const float*)d_in[0];
    const float* h0     = (const float*)d_in[1];
    const float* c0     = (const float*)d_in[2];
    const float* hebb   = (const float*)d_in[3];
    const float* w      = (const float*)d_in[4];
    const float* alpha  = (const float*)d_in[5];
    const float* Wxf = (const float*)d_in[6];  const float* bxf = (const float*)d_in[7];
    const float* Whf = (const float*)d_in[8];  const float* bhf = (const float*)d_in[9];
    const float* Wxi = (const float*)d_in[10]; const float* bxi = (const float*)d_in[11];
    const float* Whi = (const float*)d_in[12]; const float* bhi = (const float*)d_in[13];
    const float* Wxo = (const float*)d_in[14]; const float* bxo = (const float*)d_in[15];
    const float* Who = (const float*)d_in[16]; const float* bho = (const float*)d_in[17];
    const float* Wxc = (const float*)d_in[18]; const float* bxc = (const float*)d_in[19];
    const float* Wmod = (const float*)d_in[20]; const float* bmod = (const float*)d_in[21];
    const float* Wfan = (const float*)d_in[22]; const float* bfan = (const float*)d_in[23];

    float* out = (float*)d_out;
    float* ws  = (float*)d_ws;
    float* pre  = ws;                  // 4*BH
    float* part = ws + 4 * BH;         // 8*BH
    float* vbuf = ws + 12 * BH;        // BH

    // 1) fused hebbdot stream + MFMA gates (inline convert, biases folded)
    k_dot_gates<<<NHEBB + NGATE, 256, 0, stream>>>(
        hebb, h0, inputs,
        Wxf, Whf, Wxi, Whi, Wxo, Who, Wxc, w,
        bxf, bhf, bxi, bhi, bxo, bho, bxc,
        pre, part);
    // 2) finalize
    k_finalize<<<B_, 256, 0, stream>>>(pre, part, c0, alpha,
                                       Wmod, bmod, Wfan, bfan, out, vbuf);
    // 3) hebb update (reverse stream + NT stores)
    k_update<<<2048, 256, 0, stream>>>((const float4*)hebb, h0, vbuf,
                                       out + 2 * BH);
}

// Round 11
// 197.331 us; speedup vs baseline: 1.1886x; 1.1886x over previous
//
#include <hip/hip_runtime.h>
#include <hip/hip_bf16.h>
#include <math.h>

#define B_ 256
#define I_ 512
#define H_ 512
#define BH (B_*H_)
#define KA 1024          // concat K ([inputs | h0])
#define NCH 32           // h-chunks for hebbdot partials
#define HCH (H_/NCH)     // 16 rows per chunk

typedef float f4v  __attribute__((ext_vector_type(4)));
typedef short s8v  __attribute__((ext_vector_type(8)));   // 8 bf16
typedef float f32x4 __attribute__((ext_vector_type(4)));

// ws layout (floats):
// [0, 4*BH)        : pre[g][b][k]  gate pre-acts WITH biases
// [4*BH, 36*BH)    : part[ch][b][k] hebbdot partials (32 chunks, 16 MB)
// [36*BH, 37*BH)   : v[b,k]
// [37*BH, ...)     : bf16 planes Ahi, Alo, Bhi, Blo

#define A_ELEMS (256*1024)
#define B_ELEMS (2048*1024)

// ---------------------------------------------------------------------------
// K0: fp32 -> split-bf16 (hi/lo) planes. A = [inputs | h0] (256 x 1024),
// B^T = [2048 n][1024 k]: k<512 -> Wxg[ko][k]; k>=512 ->
// g<3 ? Whg[ko][k-512] : w[k-512][ko]  (w transposed here, once, coalesced).
// ---------------------------------------------------------------------------
__global__ __launch_bounds__(256) void k_convert(
    const float* __restrict__ inputs, const float* __restrict__ h0,
    const float* __restrict__ Wxf, const float* __restrict__ Whf,
    const float* __restrict__ Wxi, const float* __restrict__ Whi,
    const float* __restrict__ Wxo, const float* __restrict__ Who,
    const float* __restrict__ Wxc, const float* __restrict__ w,
    ushort* __restrict__ Ahi, ushort* __restrict__ Alo,
    ushort* __restrict__ Bhi, ushort* __restrict__ Blo) {
    const int NTOT = A_ELEMS + B_ELEMS;
    int stride = gridDim.x * blockDim.x;
    for (int f = blockIdx.x * blockDim.x + threadIdx.x; f < NTOT; f += stride) {
        float x; ushort* dhi; ushort* dlo; int idx;
        if (f < A_ELEMS) {
            idx = f;
            int m = f >> 10, k = f & 1023;
            x = (k < 512) ? inputs[m * 512 + k] : h0[m * 512 + (k - 512)];
            dhi = Ahi; dlo = Alo;
        } else {
            idx = f - A_ELEMS;
            int n = idx >> 10, k = idx & 1023;
            int g = n >> 9, ko = n & 511;
            if (k < 512) {
                const float* W = (g == 0) ? Wxf : (g == 1) ? Wxi : (g == 2) ? Wxo : Wxc;
                x = W[ko * 512 + k];
            } else if (g < 3) {
                const float* W = (g == 0) ? Whf : (g == 1) ? Whi : Who;
                x = W[ko * 512 + (k - 512)];
            } else {
                x = w[(size_t)(k - 512) * 512 + ko];   // transpose of w
            }
            dhi = Bhi; dlo = Blo;
        }
        __hip_bfloat16 h = __float2bfloat16(x);
        float hf = __bfloat162float(h);
        __hip_bfloat16 l = __float2bfloat16(x - hf);
        dhi[idx] = *(ushort*)&h;
        dlo[idx] = *(ushort*)&l;
    }
}

// ---------------------------------------------------------------------------
// K1: gate GEMM via split-bf16 MFMA. One wave per 16x16 output tile;
// K=1024 in 32 chunks; 3 MFMAs per chunk. No LDS, no barriers. Biases folded.
// ---------------------------------------------------------------------------
__global__ __launch_bounds__(256) void k_mfma_gates(
    const ushort* __restrict__ Ahi, const ushort* __restrict__ Alo,
    const ushort* __restrict__ Bhi, const ushort* __restrict__ Blo,
    const float* __restrict__ bxf, const float* __restrict__ bhf,
    const float* __restrict__ bxi, const float* __restrict__ bhi,
    const float* __restrict__ bxo, const float* __restrict__ bho,
    const float* __restrict__ bxc,
    float* __restrict__ pre) {
    int wave = threadIdx.x >> 6, lane = threadIdx.x & 63;
    int tile = blockIdx.x * 4 + wave;        // 0..2047
    int m0 = (tile & 15) << 4;               // batch tile
    int n0 = (tile >> 4) << 4;               // virtual gate column tile
    int r  = lane & 15;
    int kg = lane >> 4;                      // k-group (0..3), 8 bf16 each

    const s8v* pa_hi = (const s8v*)(Ahi + (size_t)(m0 + r) * KA + kg * 8);
    const s8v* pa_lo = (const s8v*)(Alo + (size_t)(m0 + r) * KA + kg * 8);
    const s8v* pb_hi = (const s8v*)(Bhi + (size_t)(n0 + r) * KA + kg * 8);
    const s8v* pb_lo = (const s8v*)(Blo + (size_t)(n0 + r) * KA + kg * 8);

    f32x4 acc = {0.f, 0.f, 0.f, 0.f};
    #pragma unroll 4
    for (int kc = 0; kc < 32; ++kc) {
        s8v ah = pa_hi[kc * 4];
        s8v al = pa_lo[kc * 4];
        s8v bh = pb_hi[kc * 4];
        s8v bl = pb_lo[kc * 4];
        acc = __builtin_amdgcn_mfma_f32_16x16x32_bf16(ah, bh, acc, 0, 0, 0);
        acc = __builtin_amdgcn_mfma_f32_16x16x32_bf16(ah, bl, acc, 0, 0, 0);
        acc = __builtin_amdgcn_mfma_f32_16x16x32_bf16(al, bh, acc, 0, 0, 0);
    }

    int g  = n0 >> 9;
    int ko = (n0 & 511) + r;                 // C/D: col = lane&15
    float bias;
    if (g == 0)      bias = bxf[ko] + bhf[ko];
    else if (g == 1) bias = bxi[ko] + bhi[ko];
    else if (g == 2) bias = bxo[ko] + bho[ko];
    else             bias = bxc[ko];
    #pragma unroll
    for (int j = 0; j < 4; ++j) {            // C/D: row = kg*4 + j
        int m = m0 + kg * 4 + j;
        pre[(size_t)g * BH + (size_t)m * H_ + ko] = acc[j] + bias;
    }
}

// ---------------------------------------------------------------------------
// K2: hebbdot partials, ONE latency round per thread.
// 8192 blocks (b, ch of 16 rows) x 256 thr; thread = (th half, k4 column):
// 8 independent float4 loads batched -> 8 FMA -> LDS pair-reduce -> part.
// ---------------------------------------------------------------------------
__global__ __launch_bounds__(256) void k_hebbdot(
    const float* __restrict__ hebb, const float* __restrict__ h0,
    float* __restrict__ part) {
    __shared__ float  h0s[HCH];
    __shared__ float4 red[256];
    int bid = blockIdx.x;
    int b  = bid >> 5;     // consecutive blocks share b -> contiguous hebb
    int ch = bid & 31;
    int tid = threadIdx.x;
    int tk = tid & 127;    // float4 column
    int th = tid >> 7;     // 0,1 — split 16 rows into 8+8

    const float4* hbp = (const float4*)hebb + ((size_t)b * H_ + ch * HCH) * 128;

    // batch: 8 independent loads in flight, then use
    float4 v[8];
    #pragma unroll
    for (int r = 0; r < 8; ++r)
        v[r] = hbp[(size_t)(th * 8 + r) * 128 + tk];
    if (tid < HCH) h0s[tid] = h0[b * H_ + ch * HCH + tid];
    __syncthreads();

    float4 acc = make_float4(0.f, 0.f, 0.f, 0.f);
    #pragma unroll
    for (int r = 0; r < 8; ++r) {
        float s = h0s[th * 8 + r];
        acc.x += s * v[r].x; acc.y += s * v[r].y;
        acc.z += s * v[r].z; acc.w += s * v[r].w;
    }
    red[tid] = acc;
    __syncthreads();
    if (tid < 128) {
        float4 a = red[tid], c = red[tid + 128];
        float4 o = make_float4(a.x + c.x, a.y + c.y, a.z + c.z, a.w + c.w);
        ((float4*)(part + ((size_t)ch * B_ + b) * H_))[tid] = o;
    }
}

// ---------------------------------------------------------------------------
// K3: finalize per sample (pre already has biases); dot = sum of 32 partials
// ---------------------------------------------------------------------------
__global__ __launch_bounds__(256) void k_finalize(
    const float* __restrict__ pre, const float* __restrict__ part,
    const float* __restrict__ c0, const float* __restrict__ alpha,
    const float* __restrict__ Wmod, const float* __restrict__ bmod,
    const float* __restrict__ Wfan, const float* __restrict__ bfan,
    float* __restrict__ out, float* __restrict__ v) {

    int b = blockIdx.x;
    int t = threadIdx.x;

    float c2r[2];
    float local = 0.f;
    #pragma unroll
    for (int s = 0; s < 2; ++s) {
        int k = t + s * 256;
        float dot = 0.f;
        #pragma unroll 8
        for (int c = 0; c < NCH; ++c) dot += part[((size_t)c * B_ + b) * H_ + k];
        size_t off = (size_t)b * H_ + k;
        float pf = pre[0 * BH + off];
        float pi = pre[1 * BH + off];
        float po = pre[2 * BH + off];
        float pc = pre[3 * BH + off];
        float c2 = tanhf(pc + alpha[k] * dot);
        float fg = 1.f / (1.f + expf(-pf));
        float ig = 1.f / (1.f + expf(-pi));
        float og = 1.f / (1.f + expf(-po));
        float cell = fg * c0[off] + ig * c2;
        float ha = og * tanhf(cell);
        out[off] = ha;                 // hactiv
        out[BH + off] = cell;          // cell
        c2r[s] = c2;
        local += ha * Wmod[k];
    }
    float x = local;
    #pragma unroll
    for (int o = 32; o > 0; o >>= 1) x += __shfl_down(x, o, 64);
    __shared__ float red[4];
    int wid = t >> 6, lane = t & 63;
    if (lane == 0) red[wid] = x;
    __syncthreads();
    float s4 = red[0] + red[1] + red[2] + red[3];
    float myeta = tanhf(s4 + bmod[0]);
    #pragma unroll
    for (int s = 0; s < 2; ++s) {
        int k = t + s * 256;
        size_t off = (size_t)b * H_ + k;
        v[off] = (myeta * Wfan[k] + bfan[k]) * c2r[s];
    }
}

// ---------------------------------------------------------------------------
// K4: hebb_new = clip(hebb + h0[b,h]*v[b,k], -2, 2)
// Reverse-order stream (freshest L3 lines first) + NT stores.
// ---------------------------------------------------------------------------
__global__ __launch_bounds__(256) void k_update(
    const float4* __restrict__ hebb, const float* __restrict__ h0,
    const float* __restrict__ v, float* __restrict__ out) {
    const int total = B_ * H_ * (H_ / 4);   // 16,777,216 float4
    int stride = gridDim.x * blockDim.x;    // 524,288
    int base = blockIdx.x * blockDim.x + threadIdx.x;
    for (int f = total - stride + base; f >= 0; f -= stride) {
        int k4 = f & 127;
        int h  = (f >> 7) & 511;
        int b  = f >> 16;
        float u = h0[(b << 9) + h];
        const float4* vv4 = (const float4*)v;
        float4 vv = vv4[(b << 7) + k4];
        float4 hb = hebb[f];
        f4v r;
        r.x = fminf(fmaxf(hb.x + u * vv.x, -2.f), 2.f);
        r.y = fminf(fmaxf(hb.y + u * vv.y, -2.f), 2.f);
        r.z = fminf(fmaxf(hb.z + u * vv.z, -2.f), 2.f);
        r.w = fminf(fmaxf(hb.w + u * vv.w, -2.f), 2.f);
        __builtin_nontemporal_store(r, (f4v*)(out) + f);
    }
}

// ---------------------------------------------------------------------------
extern "C" void kernel_launch(void* const* d_in, const int* in_sizes, int n_in,
                              void* d_out, int out_size, void* d_ws, size_t ws_size,
                              hipStream_t stream) {
    const float* inputs = (const float*)d_in[0];
    const float* h0     = (const float*)d_in[1];
    const float* c0     = (const float*)d_in[2];
    const float* hebb   = (const float*)d_in[3];
    const float* w      = (const float*)d_in[4];
    const float* alpha  = (const float*)d_in[5];
    const float* Wxf = (const float*)d_in[6];  const float* bxf = (const float*)d_in[7];
    const float* Whf = (const float*)d_in[8];  const float* bhf = (const float*)d_in[9];
    const float* Wxi = (const float*)d_in[10]; const float* bxi = (const float*)d_in[11];
    const float* Whi = (const float*)d_in[12]; const float* bhi = (const float*)d_in[13];
    const float* Wxo = (const float*)d_in[14]; const float* bxo = (const float*)d_in[15];
    const float* Who = (const float*)d_in[16]; const float* bho = (const float*)d_in[17];
    const float* Wxc = (const float*)d_in[18]; const float* bxc = (const float*)d_in[19];
    const float* Wmod = (const float*)d_in[20]; const float* bmod = (const float*)d_in[21];
    const float* Wfan = (const float*)d_in[22]; const float* bfan = (const float*)d_in[23];

    float* out = (float*)d_out;
    float* ws  = (float*)d_ws;
    float*  pre  = ws;                        // 4*BH
    float*  part = ws + 4 * BH;               // 32*BH
    float*  vbuf = ws + 36 * BH;              // BH
    ushort* Ahi  = (ushort*)(ws + 37 * BH);
    ushort* Alo  = Ahi + A_ELEMS;
    ushort* Bhi  = Alo + A_ELEMS;
    ushort* Blo  = Bhi + B_ELEMS;

    // 0) split-bf16 conversion
    k_convert<<<2048, 256, 0, stream>>>(inputs, h0,
        Wxf, Whf, Wxi, Whi, Wxo, Who, Wxc, w, Ahi, Alo, Bhi, Blo);
    // 1) gate GEMM on matrix cores (biases folded)
    k_mfma_gates<<<512, 256, 0, stream>>>(Ahi, Alo, Bhi, Blo,
        bxf, bhf, bxi, bhi, bxo, bho, bxc, pre);
    // 2) hebbdot partials: one latency round per thread, 8192 blocks
    k_hebbdot<<<B_ * NCH, 256, 0, stream>>>(hebb, h0, part);
    // 3) finalize
    k_finalize<<<B_, 256, 0, stream>>>(pre, part, c0, alpha,
                                       Wmod, bmod, Wfan, bfan, out, vbuf);
    // 4) hebb update (reverse stream + NT stores)
    k_update<<<2048, 256, 0, stream>>>((const float4*)hebb, h0, vbuf,
                                       out + 2 * BH);
}